// Round 3
// baseline (214.780 us; speedup 1.0000x reference)
//
#include <hip/hip_runtime.h>
#include <math.h>

#define NRAYS 8192
#define T 128
#define H 128
#define SHD 16

using short8 = __attribute__((ext_vector_type(8))) short;
using f32x4  = __attribute__((ext_vector_type(4))) float;
using f32x2  = __attribute__((ext_vector_type(2))) float;

__device__ __forceinline__ float fexp(float x) {
  return exp2f(x * 1.44269504088896341f);
}
__device__ __forceinline__ float softplus_f(float x) {
  return fmaxf(x, 0.f) + 0.693147180559945309f * log2f(1.f + fexp(-fabsf(x)));
}
__device__ __forceinline__ float sigmoid_f(float x) {
  return __builtin_amdgcn_rcpf(1.f + fexp(-x));
}

// RNE float->bf16 (preprocess only)
__device__ __forceinline__ unsigned f2bf(float f) {
  unsigned u = __float_as_uint(f);
  return (u + 0x7fffu + ((u >> 16) & 1u)) >> 16;
}

// RNE bf16 pack of a float pair: single VALU op (v_cvt_pk_bf16_f32, gfx950)
__device__ __forceinline__ unsigned pk2(f32x2 h) {
  unsigned r;
  asm("v_cvt_pk_bf16_f32 %0, %1, %2" : "=v"(r) : "v"(h[0]), "v"(h[1]));
  return r;
}

__device__ __forceinline__ float rflf(float v) {
  return __builtin_bit_cast(float, __builtin_amdgcn_readfirstlane(__builtin_bit_cast(int, v)));
}

// cross-lane gather: byteaddr = src_lane*4 (+folded imm); lane crossbar, no bank conflicts
__device__ __forceinline__ float bpermf(int byteaddr, float v) {
  return __builtin_bit_cast(float, __builtin_amdgcn_ds_bpermute(byteaddr, __builtin_bit_cast(int, v)));
}

// ---- preprocess (unchanged) ----
// w2t: bf16 W2^T, XOR-swizzled: w2t[n*128 + p], octet o=(p>>3)^(n&7), k=o*8+(p&7)
//      holds W2[k][n]  -> conflict-free ds_read_b128 A-frag pattern (R3/R5-verified)
// woutf[(kk*64+L)*8+j]: epilogue A-frag A[m=c][k=kk*32+g*8+j]:
//   m=0 -> Wd, m=1..3 -> Wc[:,m-1], m>=4 -> 0   (L = g*16+c)
// rayp_all[r][8] = {tfar_c, dnorm, active, cp0, cp1, cp2, tnear, 0}  (AABB + SH)
__global__ void preprocess(const float* __restrict__ W2, const float* __restrict__ Wd,
                           const float* __restrict__ Wc, const float* __restrict__ bc,
                           const float* __restrict__ origins, const float* __restrict__ dirs,
                           unsigned short* __restrict__ w2t,
                           unsigned short* __restrict__ woutf,
                           float* __restrict__ rayp_all) {
  const int t = blockIdx.x * 256 + threadIdx.x;
  if (t < 16384) {
    const int n = t >> 7, p = t & 127;
    const int o = (p >> 3) ^ (n & 7);
    const int k = o * 8 + (p & 7);
    w2t[t] = (unsigned short)f2bf(W2[k * 128 + n]);
  }
  if (t < 2048) {
    const int kk = t >> 9, L = (t >> 3) & 63, j = t & 7;
    const int c = L & 15, g = L >> 4;
    const int k = kk * 32 + g * 8 + j;
    float v = 0.f;
    if (c == 0) v = Wd[k];
    else if (c < 4) v = Wc[k * 3 + (c - 1)];
    woutf[t] = (unsigned short)f2bf(v);
  }
  if (t < NRAYS) {
    const float ox = origins[t*3+0], oy = origins[t*3+1], oz = origins[t*3+2];
    const float dx = dirs[t*3+0],  dy = dirs[t*3+1],  dz = dirs[t*3+2];
    const float ix = 1.f/dx, iy = 1.f/dy, iz = 1.f/dz;
    const float t1x = (-1.f-ox)*ix, t2x = (1.f-ox)*ix;
    const float t1y = (-1.f-oy)*iy, t2y = (1.f-oy)*iy;
    const float t1z = (-1.f-oz)*iz, t2z = (1.f-oz)*iz;
    float tnear = fmaxf(fmaxf(fminf(t1x,t2x), fminf(t1y,t2y)), fminf(t1z,t2z));
    tnear = fmaxf(tnear, 0.f);
    const float tfar = fminf(fminf(fmaxf(t1x,t2x), fmaxf(t1y,t2y)), fmaxf(t1z,t2z));
    const bool  active = tfar > tnear;
    const float tfar_c = fmaxf(tfar, tnear + 1e-3f);
    const float dnorm = sqrtf(dx*dx + dy*dy + dz*dz);
    const float nx = dx/dnorm, ny = dy/dnorm, nz = dz/dnorm;
    const float x2 = nx*nx, y2 = ny*ny, z2 = nz*nz;
    const float xy = nx*ny, yz = ny*nz, xz = nx*nz;
    float ynm[16];
    ynm[0]  = 0.282094791773878f;
    ynm[1]  = -0.48860251190292f*ny;
    ynm[2]  = 0.48860251190292f*nz;
    ynm[3]  = -0.48860251190292f*nx;
    ynm[4]  = 1.0925484305920792f*xy;
    ynm[5]  = -1.0925484305920792f*yz;
    ynm[6]  = 0.94617469575756f*z2 - 0.31539156525252f;
    ynm[7]  = -1.0925484305920792f*xz;
    ynm[8]  = 0.5462742152960396f*(x2-y2);
    ynm[9]  = 0.5900435899266435f*ny*(-3.f*x2+y2);
    ynm[10] = 2.8906114426405538f*xy*nz;
    ynm[11] = 0.4570457994644658f*ny*(1.f-5.f*z2);
    ynm[12] = 0.3731763325901154f*nz*(5.f*z2-3.f);
    ynm[13] = 0.4570457994644658f*nx*(1.f-5.f*z2);
    ynm[14] = 1.445305721320277f*nz*(x2-y2);
    ynm[15] = 0.5900435899266435f*nx*(-x2+3.f*y2);
    float cp0 = bc[0], cp1 = bc[1], cp2 = bc[2];
    #pragma unroll
    for (int s = 0; s < SHD; ++s) {
      cp0 = fmaf(ynm[s], Wc[(H+s)*3+0], cp0);
      cp1 = fmaf(ynm[s], Wc[(H+s)*3+1], cp1);
      cp2 = fmaf(ynm[s], Wc[(H+s)*3+2], cp2);
    }
    rayp_all[t*8+0] = tfar_c;
    rayp_all[t*8+1] = dnorm;
    rayp_all[t*8+2] = active ? 1.f : 0.f;
    rayp_all[t*8+3] = cp0;
    rayp_all[t*8+4] = cp1;
    rayp_all[t*8+5] = cp2;
    rayp_all[t*8+6] = tnear;
    rayp_all[t*8+7] = 0.f;
  }
}

// 4 rays per block, ONE WAVE PER RAY — no inter-wave coupling after the single
// staging barrier. Per wave: 4 sample-tile passes (stp = 32 samples each), each
// pass = main-loop MFMA (64) + epilogue MFMA (8) + online transmittance.
// Per-ray state (ts, mask*delta*dnorm, W1 base/slope) lives in registers,
// gathered cross-lane via ds_bpermute.  Masked samples: dmn=0 -> sd=0 ->
// wgt = exp(-csum)-exp(-csum) == 0 exactly, so no explicit color masking needed.
// LDS: Bs 32768 + b2s 512 + As2 5120 = 38400 B -> 4 blocks/CU (16 waves).
__global__ __launch_bounds__(256, 4) void nerf_render(
    const float* __restrict__ origins, const float* __restrict__ dirs,
    const float* __restrict__ u, const float* __restrict__ W1,
    const float* __restrict__ b1, const float* __restrict__ b2,
    const float* __restrict__ bd, const unsigned short* __restrict__ w2t,
    const unsigned short* __restrict__ woutf, const float* __restrict__ rayp_all,
    float* __restrict__ out)
{
  const int tid = threadIdx.x;
  const int L = tid & 63;
  const int w = tid >> 6;
  const int g = L >> 4;
  const int c = L & 15;
  const int ray = blockIdx.x * 4 + w;

  __shared__ __align__(16) short Bs[16384];     // swizzled W2^T (shared by all 4 waves)
  __shared__ __align__(16) float b2s[128];      // b2 (acc re-init each stp)
  __shared__ __align__(16) short As2[4 * 640];  // per-wave epilogue slab (40-short stride, 16B-aligned)

  // ---- stage W2 + b2 (cooperative, the ONLY barrier) ----
  {
    const float4* src = (const float4*)w2t;
    float4* dst = (float4*)Bs;
    #pragma unroll
    for (int i = 0; i < 8; ++i) dst[tid + i * 256] = src[tid + i * 256];
  }
  if (tid < 128) b2s[tid] = b2[tid];

  // ---- per-ray scalars -> SGPR (wave-uniform) ----
  const float tfar_c = rflf(rayp_all[ray*8+0]);
  const float dnorm  = rflf(rayp_all[ray*8+1]);
  const float actf   = rflf(rayp_all[ray*8+2]);
  const float cp0    = rflf(rayp_all[ray*8+3]);
  const float cp1    = rflf(rayp_all[ray*8+4]);
  const float cp2    = rflf(rayp_all[ray*8+5]);
  const float tnear  = rflf(rayp_all[ray*8+6]);
  const float bd0    = rflf(bd[0]);
  const float ox = rflf(origins[ray*3+0]);
  const float oy = rflf(origins[ray*3+1]);
  const float oz = rflf(origins[ray*3+2]);
  const float dx = rflf(dirs[ray*3+0]);
  const float dy = rflf(dirs[ray*3+1]);
  const float dz = rflf(dirs[ray*3+2]);
  const bool active = actf != 0.f;

  // ---- per-sample setup in registers: lane L holds samples L and 64+L ----
  float ts_q[2], dmn_q[2], mk_q[2];
  #pragma unroll
  for (int q = 0; q < 2; ++q) {
    const int s = q*64 + L;
    const float uv = u[ray*T + s];
    const float frac = ((float)s + uv) * (1.f/(float)T);
    const float tt = fmaf(tfar_c - tnear, frac, tnear);
    ts_q[q] = tt;
    const float px = fmaf(dx, tt, ox);
    const float py = fmaf(dy, tt, oy);
    const float pz = fmaf(dz, tt, oz);
    mk_q[q] = ((fabsf(px) <= 1.f) && (fabsf(py) <= 1.f) && (fabsf(pz) <= 1.f) && active)
                ? 1.f : 0.f;
  }
  {
    const float t64 = __shfl(ts_q[1], 0);
    float tn0 = __shfl(ts_q[0], (L+1) & 63);
    float tn1 = __shfl(ts_q[1], (L+1) & 63);
    tn0 = (L == 63) ? t64 : tn0;
    tn1 = (L == 63) ? tfar_c * 10.f : tn1;
    dmn_q[0] = mk_q[0] * (tn0 - ts_q[0]) * dnorm;   // mask*delta*dnorm (0 if masked)
    dmn_q[1] = mk_q[1] * (tn1 - ts_q[1]) * dnorm;
  }
  // W1 affine per hidden unit: lane L holds units L and 64+L
  float base_q[2], slope_q[2];
  #pragma unroll
  for (int q = 0; q < 2; ++q) {
    const int hh = q*64 + L;
    const float w0v = W1[hh], w1v = W1[H + hh], w2v = W1[2*H + hh];
    base_q[q]  = fmaf(ox, w0v, fmaf(oy, w1v, fmaf(oz, w2v, b1[hh])));
    slope_q[q] = fmaf(dx, w0v, fmaf(dy, w1v, dz * w2v));
  }

  // epilogue A-frags (global, L2-hot)
  short8 wa[4];
  #pragma unroll
  for (int kk = 0; kk < 4; ++kk)
    wa[kk] = *(const short8*)&woutf[(kk*64 + L)*8];

  __syncthreads();   // Bs/b2s ready; waves fully independent from here on

  short* As2w = As2 + w * 640;
  const int permbase = g * 32;               // byte addr of unit g*8 within the wave
  const f32x2 zero2 = {0.f, 0.f};
  f32x4 acc[2][8];
  float csum = 0.f, pw = 0.f, pxc = 0.f, pyc = 0.f, pzc = 0.f;

  #pragma unroll
  for (int stp = 0; stp < 4; ++stp) {
    const int q = stp >> 1;
    // this pass covers samples stp*32 + {c (tm0), 16+c (tm1)}
    const int i0 = ((stp*32 + c) & 63) * 4;
    const int i1 = ((stp*32 + 16 + c) & 63) * 4;
    const float t0 = bpermf(i0, ts_q[q]);
    const float t1 = bpermf(i1, ts_q[q]);
    const float d0 = bpermf(i0, dmn_q[q]);
    const float d1 = bpermf(i1, dmn_q[q]);
    const f32x2 tz0 = {t0, t0}, tz1 = {t1, t1};

    // acc init = b2 (broadcast ds_read_b128)
    #pragma unroll
    for (int mt = 0; mt < 8; ++mt) {
      const f32x4 bv = *(const f32x4*)&b2s[mt*16 + g*4];
      acc[0][mt] = bv; acc[1][mt] = bv;
    }

    // ---- fused affine-layer1 (bpermute + packed VALU) + layer2 MFMA ----
    #pragma unroll
    for (int ks = 0; ks < 4; ++ks) {
      const int kq = ks >> 1;
      const int pb = permbase + ((ks & 1) << 7);   // unit (ks&1)*32 + g*8
      float bj[8], sj[8];
      #pragma unroll
      for (int j = 0; j < 8; ++j) {
        bj[j] = bpermf(pb + j*4, base_q[kq]);
        sj[j] = bpermf(pb + j*4, slope_q[kq]);
      }
      const f32x2 b01 = {bj[0], bj[1]}, b23 = {bj[2], bj[3]};
      const f32x2 b45 = {bj[4], bj[5]}, b67 = {bj[6], bj[7]};
      const f32x2 s01 = {sj[0], sj[1]}, s23 = {sj[2], sj[3]};
      const f32x2 s45 = {sj[4], sj[5]}, s67 = {sj[6], sj[7]};
      const f32x2 a01 = __builtin_elementwise_max(__builtin_elementwise_fma(tz0, s01, b01), zero2);
      const f32x2 a23 = __builtin_elementwise_max(__builtin_elementwise_fma(tz0, s23, b23), zero2);
      const f32x2 a45 = __builtin_elementwise_max(__builtin_elementwise_fma(tz0, s45, b45), zero2);
      const f32x2 a67 = __builtin_elementwise_max(__builtin_elementwise_fma(tz0, s67, b67), zero2);
      const f32x2 e01 = __builtin_elementwise_max(__builtin_elementwise_fma(tz1, s01, b01), zero2);
      const f32x2 e23 = __builtin_elementwise_max(__builtin_elementwise_fma(tz1, s23, b23), zero2);
      const f32x2 e45 = __builtin_elementwise_max(__builtin_elementwise_fma(tz1, s45, b45), zero2);
      const f32x2 e67 = __builtin_elementwise_max(__builtin_elementwise_fma(tz1, s67, b67), zero2);
      union U { uint4 u; short8 s; } A0, A1;
      A0.u = make_uint4(pk2(a01), pk2(a23), pk2(a45), pk2(a67));
      A1.u = make_uint4(pk2(e01), pk2(e23), pk2(e45), pk2(e67));
      const int swb = ((ks*4 + g) ^ (c & 7)) * 8;   // swizzled octet (conflict-free, proven)
      #pragma unroll
      for (int mt = 0; mt < 8; ++mt) {
        const short8 wf = *(const short8*)&Bs[(mt*16 + c)*128 + swb];
        acc[0][mt] = __builtin_amdgcn_mfma_f32_16x16x32_bf16(wf, A0.s, acc[0][mt], 0, 0, 0);
        acc[1][mt] = __builtin_amdgcn_mfma_f32_16x16x32_bf16(wf, A1.s, acc[1][mt], 0, 0, 0);
      }
    }

    // ---- epilogue: relu -> bf16 slab -> 4-k-step MFMA dot with Wout ----
    f32x4 osig[2];
    #pragma unroll
    for (int tm = 0; tm < 2; ++tm) {
      f32x4 oacc;
      oacc[0] = 0.f; oacc[1] = 0.f; oacc[2] = 0.f; oacc[3] = 0.f;
      #pragma unroll
      for (int kk = 0; kk < 4; ++kk) {
        #pragma unroll
        for (int i = 0; i < 2; ++i) {
          const f32x4 a = acc[tm][kk*2 + i];
          const f32x2 h01 = __builtin_elementwise_max((f32x2){a[0], a[1]}, zero2);
          const f32x2 h23 = __builtin_elementwise_max((f32x2){a[2], a[3]}, zero2);
          *(uint2*)&As2w[c*40 + i*16 + g*4] = make_uint2(pk2(h01), pk2(h23));
        }
        const short8 hbf = *(const short8*)&As2w[c*40 + g*8];
        oacc = __builtin_amdgcn_mfma_f32_16x16x32_bf16(wa[kk], hbf, oacc, 0, 0, 0);
      }
      osig[tm] = oacc;   // lanes g==0: {sigma_pre, c0, c1, c2}; g>0 lanes: zeros
    }

    // ---- online transmittance for these 32 samples (valid in lanes 0..15) ----
    const float sd0 = softplus_f(osig[0][0] + bd0) * d0;
    const float sd1 = softplus_f(osig[1][0] + bd0) * d1;
    float p0 = sd0;
    #pragma unroll
    for (int off = 1; off < 16; off <<= 1) {
      const float tpp = __shfl_up(p0, off, 16);
      p0 += ((L & 15) >= off) ? tpp : 0.f;
    }
    const float tot0 = __shfl(p0, 15);        // group-0 lane 15 -> all lanes
    float p1 = sd1;
    #pragma unroll
    for (int off = 1; off < 16; off <<= 1) {
      const float tpp = __shfl_up(p1, off, 16);
      p1 += ((L & 15) >= off) ? tpp : 0.f;
    }
    const float tot1 = __shfl(p1, 15);
    const float cs0 = csum + p0;
    const float cs1 = csum + tot0 + p1;
    csum += tot0 + tot1;
    const float w0 = fexp(sd0 - cs0) - fexp(-cs0);   // == 0 exactly when sd0 == 0
    const float w1 = fexp(sd1 - cs1) - fexp(-cs1);
    pw  += w0 + w1;
    pxc += w0 * sigmoid_f(osig[0][1] + cp0) + w1 * sigmoid_f(osig[1][1] + cp0);
    pyc += w0 * sigmoid_f(osig[0][2] + cp1) + w1 * sigmoid_f(osig[1][2] + cp1);
    pzc += w0 * sigmoid_f(osig[0][3] + cp2) + w1 * sigmoid_f(osig[1][3] + cp2);
  }

  // ---- per-ray reduction over lanes 0..15, store from lane 0 ----
  #pragma unroll
  for (int off = 1; off < 16; off <<= 1) {
    pw  += __shfl_xor(pw, off);
    pxc += __shfl_xor(pxc, off);
    pyc += __shfl_xor(pyc, off);
    pzc += __shfl_xor(pzc, off);
  }
  if (L == 0) {
    float4 o;
    o.x = active ? pxc : 0.f;
    o.y = active ? pyc : 0.f;
    o.z = active ? pzc : 0.f;
    o.w = active ? pw  : 0.f;
    *(float4*)&out[ray*4] = o;
  }
}

extern "C" void kernel_launch(void* const* d_in, const int* in_sizes, int n_in,
                              void* d_out, int out_size, void* d_ws, size_t ws_size,
                              hipStream_t stream) {
  const float* origins = (const float*)d_in[0];
  const float* dirs    = (const float*)d_in[1];
  const float* u       = (const float*)d_in[2];
  const float* W1      = (const float*)d_in[3];
  const float* b1      = (const float*)d_in[4];
  const float* W2      = (const float*)d_in[5];
  const float* b2      = (const float*)d_in[6];
  const float* Wd      = (const float*)d_in[7];
  const float* bd      = (const float*)d_in[8];
  const float* Wc      = (const float*)d_in[9];
  const float* bc      = (const float*)d_in[10];

  unsigned short* w2t      = (unsigned short*)d_ws;
  unsigned short* woutf    = (unsigned short*)((char*)d_ws + 32768);
  float*          rayp_all = (float*)((char*)d_ws + 36864);

  preprocess<<<64, 256, 0, stream>>>(W2, Wd, Wc, bc, origins, dirs,
                                     w2t, woutf, rayp_all);
  nerf_render<<<NRAYS/4, 256, 0, stream>>>(origins, dirs, u, W1, b1, b2, bd,
                                           w2t, woutf, rayp_all, (float*)d_out);
}

// Round 5
// 141.990 us; speedup vs baseline: 1.5126x; 1.5126x over previous
//
#include <hip/hip_runtime.h>
#include <math.h>

#define NRAYS 8192
#define T 128
#define H 128
#define SHD 16

using short8 = __attribute__((ext_vector_type(8))) short;
using f32x4  = __attribute__((ext_vector_type(4))) float;
using f32x2  = __attribute__((ext_vector_type(2))) float;

__device__ __forceinline__ float fexp(float x) {
  return exp2f(x * 1.44269504088896341f);
}
__device__ __forceinline__ float softplus_f(float x) {
  return fmaxf(x, 0.f) + 0.693147180559945309f * log2f(1.f + fexp(-fabsf(x)));
}
__device__ __forceinline__ float sigmoid_f(float x) {
  return __builtin_amdgcn_rcpf(1.f + fexp(-x));
}

// RNE float->bf16 (preprocess only)
__device__ __forceinline__ unsigned f2bf(float f) {
  unsigned u = __float_as_uint(f);
  return (u + 0x7fffu + ((u >> 16) & 1u)) >> 16;
}

// RNE bf16 pack of a float pair: single VALU op (v_cvt_pk_bf16_f32, gfx950)
__device__ __forceinline__ unsigned pk2(f32x2 h) {
  unsigned r;
  asm("v_cvt_pk_bf16_f32 %0, %1, %2" : "=v"(r) : "v"(h[0]), "v"(h[1]));
  return r;
}

__device__ __forceinline__ float rflf(float v) {
  return __builtin_bit_cast(float, __builtin_amdgcn_readfirstlane(__builtin_bit_cast(int, v)));
}

// cross-lane gather: byteaddr = src_lane*4 (+folded imm); lane crossbar, no bank conflicts
__device__ __forceinline__ float bpermf(int byteaddr, float v) {
  return __builtin_bit_cast(float, __builtin_amdgcn_ds_bpermute(byteaddr, __builtin_bit_cast(int, v)));
}

// ---- preprocess (unchanged) ----
// w2t: bf16 W2^T, XOR-swizzled: w2t[n*128 + p], octet o=(p>>3)^(n&7), k=o*8+(p&7)
//      holds W2[k][n]  -> conflict-free ds_read_b128 A-frag pattern (R3/R5-verified)
// woutf[(kk*64+L)*8+j]: epilogue A-frag A[m=c][k=kk*32+g*8+j]:
//   m=0 -> Wd, m=1..3 -> Wc[:,m-1], m>=4 -> 0   (L = g*16+c)
// rayp_all[r][8] = {tfar_c, dnorm, active, cp0, cp1, cp2, tnear, 0}  (AABB + SH)
__global__ void preprocess(const float* __restrict__ W2, const float* __restrict__ Wd,
                           const float* __restrict__ Wc, const float* __restrict__ bc,
                           const float* __restrict__ origins, const float* __restrict__ dirs,
                           unsigned short* __restrict__ w2t,
                           unsigned short* __restrict__ woutf,
                           float* __restrict__ rayp_all) {
  const int t = blockIdx.x * 256 + threadIdx.x;
  if (t < 16384) {
    const int n = t >> 7, p = t & 127;
    const int o = (p >> 3) ^ (n & 7);
    const int k = o * 8 + (p & 7);
    w2t[t] = (unsigned short)f2bf(W2[k * 128 + n]);
  }
  if (t < 2048) {
    const int kk = t >> 9, L = (t >> 3) & 63, j = t & 7;
    const int c = L & 15, g = L >> 4;
    const int k = kk * 32 + g * 8 + j;
    float v = 0.f;
    if (c == 0) v = Wd[k];
    else if (c < 4) v = Wc[k * 3 + (c - 1)];
    woutf[t] = (unsigned short)f2bf(v);
  }
  if (t < NRAYS) {
    const float ox = origins[t*3+0], oy = origins[t*3+1], oz = origins[t*3+2];
    const float dx = dirs[t*3+0],  dy = dirs[t*3+1],  dz = dirs[t*3+2];
    const float ix = 1.f/dx, iy = 1.f/dy, iz = 1.f/dz;
    const float t1x = (-1.f-ox)*ix, t2x = (1.f-ox)*ix;
    const float t1y = (-1.f-oy)*iy, t2y = (1.f-oy)*iy;
    const float t1z = (-1.f-oz)*iz, t2z = (1.f-oz)*iz;
    float tnear = fmaxf(fmaxf(fminf(t1x,t2x), fminf(t1y,t2y)), fminf(t1z,t2z));
    tnear = fmaxf(tnear, 0.f);
    const float tfar = fminf(fminf(fmaxf(t1x,t2x), fmaxf(t1y,t2y)), fmaxf(t1z,t2z));
    const bool  active = tfar > tnear;
    const float tfar_c = fmaxf(tfar, tnear + 1e-3f);
    const float dnorm = sqrtf(dx*dx + dy*dy + dz*dz);
    const float nx = dx/dnorm, ny = dy/dnorm, nz = dz/dnorm;
    const float x2 = nx*nx, y2 = ny*ny, z2 = nz*nz;
    const float xy = nx*ny, yz = ny*nz, xz = nx*nz;
    float ynm[16];
    ynm[0]  = 0.282094791773878f;
    ynm[1]  = -0.48860251190292f*ny;
    ynm[2]  = 0.48860251190292f*nz;
    ynm[3]  = -0.48860251190292f*nx;
    ynm[4]  = 1.0925484305920792f*xy;
    ynm[5]  = -1.0925484305920792f*yz;
    ynm[6]  = 0.94617469575756f*z2 - 0.31539156525252f;
    ynm[7]  = -1.0925484305920792f*xz;
    ynm[8]  = 0.5462742152960396f*(x2-y2);
    ynm[9]  = 0.5900435899266435f*ny*(-3.f*x2+y2);
    ynm[10] = 2.8906114426405538f*xy*nz;
    ynm[11] = 0.4570457994644658f*ny*(1.f-5.f*z2);
    ynm[12] = 0.3731763325901154f*nz*(5.f*z2-3.f);
    ynm[13] = 0.4570457994644658f*nx*(1.f-5.f*z2);
    ynm[14] = 1.445305721320277f*nz*(x2-y2);
    ynm[15] = 0.5900435899266435f*nx*(-x2+3.f*y2);
    float cp0 = bc[0], cp1 = bc[1], cp2 = bc[2];
    #pragma unroll
    for (int s = 0; s < SHD; ++s) {
      cp0 = fmaf(ynm[s], Wc[(H+s)*3+0], cp0);
      cp1 = fmaf(ynm[s], Wc[(H+s)*3+1], cp1);
      cp2 = fmaf(ynm[s], Wc[(H+s)*3+2], cp2);
    }
    rayp_all[t*8+0] = tfar_c;
    rayp_all[t*8+1] = dnorm;
    rayp_all[t*8+2] = active ? 1.f : 0.f;
    rayp_all[t*8+3] = cp0;
    rayp_all[t*8+4] = cp1;
    rayp_all[t*8+5] = cp2;
    rayp_all[t*8+6] = tnear;
    rayp_all[t*8+7] = 0.f;
  }
}

// 4 rays per block, ONE WAVE PER RAY — no inter-wave coupling after the single
// staging barrier. Per wave: 4 sample-tile passes (stp = 32 samples each), each
// pass = main-loop MFMA (64) + epilogue MFMA (8) + online transmittance.
// Per-ray state (ts, mask*delta*dnorm, W1 base/slope) lives in registers,
// gathered cross-lane via ds_bpermute.  Masked samples: dmn=0 -> sd=0 ->
// wgt = exp(-csum)-exp(-csum) == 0 exactly, so no explicit color masking needed.
// LDS: Bs 32768 + b2s 512 + As2 5120 = 38400 B.
// launch_bounds(256, 2): R3's (256,4) capped the allocator at 128 regs/wave
// while the wave needs ~170 -> 285 MB scratch writes (WRITE_SIZE counter) and
// a 2x regression. Budget 256 regs/wave eliminates spill; occupancy follows
// actual allocation (~8-12 waves/CU), fine since waves are independent.
__global__ __launch_bounds__(256, 2) void nerf_render(
    const float* __restrict__ origins, const float* __restrict__ dirs,
    const float* __restrict__ u, const float* __restrict__ W1,
    const float* __restrict__ b1, const float* __restrict__ b2,
    const float* __restrict__ bd, const unsigned short* __restrict__ w2t,
    const unsigned short* __restrict__ woutf, const float* __restrict__ rayp_all,
    float* __restrict__ out)
{
  const int tid = threadIdx.x;
  const int L = tid & 63;
  const int w = tid >> 6;
  const int g = L >> 4;
  const int c = L & 15;
  const int ray = blockIdx.x * 4 + w;

  __shared__ __align__(16) short Bs[16384];     // swizzled W2^T (shared by all 4 waves)
  __shared__ __align__(16) float b2s[128];      // b2 (acc re-init each stp)
  __shared__ __align__(16) short As2[4 * 640];  // per-wave epilogue slab (40-short stride, 16B-aligned)

  // ---- stage W2 + b2 (cooperative, the ONLY barrier) ----
  {
    const float4* src = (const float4*)w2t;
    float4* dst = (float4*)Bs;
    #pragma unroll
    for (int i = 0; i < 8; ++i) dst[tid + i * 256] = src[tid + i * 256];
  }
  if (tid < 128) b2s[tid] = b2[tid];

  // ---- per-ray scalars -> SGPR (wave-uniform) ----
  const float tfar_c = rflf(rayp_all[ray*8+0]);
  const float dnorm  = rflf(rayp_all[ray*8+1]);
  const float actf   = rflf(rayp_all[ray*8+2]);
  const float cp0    = rflf(rayp_all[ray*8+3]);
  const float cp1    = rflf(rayp_all[ray*8+4]);
  const float cp2    = rflf(rayp_all[ray*8+5]);
  const float tnear  = rflf(rayp_all[ray*8+6]);
  const float bd0    = rflf(bd[0]);
  const float ox = rflf(origins[ray*3+0]);
  const float oy = rflf(origins[ray*3+1]);
  const float oz = rflf(origins[ray*3+2]);
  const float dx = rflf(dirs[ray*3+0]);
  const float dy = rflf(dirs[ray*3+1]);
  const float dz = rflf(dirs[ray*3+2]);
  const bool active = actf != 0.f;

  // ---- per-sample setup in registers: lane L holds samples L and 64+L ----
  float ts_q[2], dmn_q[2];
  #pragma unroll
  for (int q = 0; q < 2; ++q) {
    const int s = q*64 + L;
    const float uv = u[ray*T + s];
    const float frac = ((float)s + uv) * (1.f/(float)T);
    const float tt = fmaf(tfar_c - tnear, frac, tnear);
    ts_q[q] = tt;
    const float px = fmaf(dx, tt, ox);
    const float py = fmaf(dy, tt, oy);
    const float pz = fmaf(dz, tt, oz);
    dmn_q[q] = ((fabsf(px) <= 1.f) && (fabsf(py) <= 1.f) && (fabsf(pz) <= 1.f) && active)
                ? 1.f : 0.f;   // mask for now; folded into delta*dnorm below
  }
  {
    const float t64 = __shfl(ts_q[1], 0);
    float tn0 = __shfl(ts_q[0], (L+1) & 63);
    float tn1 = __shfl(ts_q[1], (L+1) & 63);
    tn0 = (L == 63) ? t64 : tn0;
    tn1 = (L == 63) ? tfar_c * 10.f : tn1;
    dmn_q[0] = dmn_q[0] * (tn0 - ts_q[0]) * dnorm;   // mask*delta*dnorm (0 if masked)
    dmn_q[1] = dmn_q[1] * (tn1 - ts_q[1]) * dnorm;
  }
  // W1 affine per hidden unit: lane L holds units L and 64+L
  float base_q[2], slope_q[2];
  #pragma unroll
  for (int q = 0; q < 2; ++q) {
    const int hh = q*64 + L;
    const float w0v = W1[hh], w1v = W1[H + hh], w2v = W1[2*H + hh];
    base_q[q]  = fmaf(ox, w0v, fmaf(oy, w1v, fmaf(oz, w2v, b1[hh])));
    slope_q[q] = fmaf(dx, w0v, fmaf(dy, w1v, dz * w2v));
  }

  // epilogue A-frags (global, L2-hot)
  short8 wa[4];
  #pragma unroll
  for (int kk = 0; kk < 4; ++kk)
    wa[kk] = *(const short8*)&woutf[(kk*64 + L)*8];

  __syncthreads();   // Bs/b2s ready; waves fully independent from here on

  short* As2w = As2 + w * 640;
  const int permbase = g * 32;               // byte addr of unit g*8 within the wave
  const f32x2 zero2 = {0.f, 0.f};
  f32x4 acc[2][8];
  float csum = 0.f, pw = 0.f, pxc = 0.f, pyc = 0.f, pzc = 0.f;

  #pragma unroll
  for (int stp = 0; stp < 4; ++stp) {
    const int q = stp >> 1;
    // this pass covers samples stp*32 + {c (tm0), 16+c (tm1)}
    const int i0 = ((stp*32 + c) & 63) * 4;
    const int i1 = ((stp*32 + 16 + c) & 63) * 4;
    const float t0 = bpermf(i0, ts_q[q]);
    const float t1 = bpermf(i1, ts_q[q]);
    const float d0 = bpermf(i0, dmn_q[q]);
    const float d1 = bpermf(i1, dmn_q[q]);
    const f32x2 tz0 = {t0, t0}, tz1 = {t1, t1};

    // acc init = b2 (broadcast ds_read_b128)
    #pragma unroll
    for (int mt = 0; mt < 8; ++mt) {
      const f32x4 bv = *(const f32x4*)&b2s[mt*16 + g*4];
      acc[0][mt] = bv; acc[1][mt] = bv;
    }

    // ---- fused affine-layer1 (bpermute + packed VALU) + layer2 MFMA ----
    #pragma unroll
    for (int ks = 0; ks < 4; ++ks) {
      const int kq = ks >> 1;
      const int pb = permbase + ((ks & 1) << 7);   // unit (ks&1)*32 + g*8
      float bj[8], sj[8];
      #pragma unroll
      for (int j = 0; j < 8; ++j) {
        bj[j] = bpermf(pb + j*4, base_q[kq]);
        sj[j] = bpermf(pb + j*4, slope_q[kq]);
      }
      const f32x2 b01 = {bj[0], bj[1]}, b23 = {bj[2], bj[3]};
      const f32x2 b45 = {bj[4], bj[5]}, b67 = {bj[6], bj[7]};
      const f32x2 s01 = {sj[0], sj[1]}, s23 = {sj[2], sj[3]};
      const f32x2 s45 = {sj[4], sj[5]}, s67 = {sj[6], sj[7]};
      const f32x2 a01 = __builtin_elementwise_max(__builtin_elementwise_fma(tz0, s01, b01), zero2);
      const f32x2 a23 = __builtin_elementwise_max(__builtin_elementwise_fma(tz0, s23, b23), zero2);
      const f32x2 a45 = __builtin_elementwise_max(__builtin_elementwise_fma(tz0, s45, b45), zero2);
      const f32x2 a67 = __builtin_elementwise_max(__builtin_elementwise_fma(tz0, s67, b67), zero2);
      const f32x2 e01 = __builtin_elementwise_max(__builtin_elementwise_fma(tz1, s01, b01), zero2);
      const f32x2 e23 = __builtin_elementwise_max(__builtin_elementwise_fma(tz1, s23, b23), zero2);
      const f32x2 e45 = __builtin_elementwise_max(__builtin_elementwise_fma(tz1, s45, b45), zero2);
      const f32x2 e67 = __builtin_elementwise_max(__builtin_elementwise_fma(tz1, s67, b67), zero2);
      union U { uint4 u; short8 s; } A0, A1;
      A0.u = make_uint4(pk2(a01), pk2(a23), pk2(a45), pk2(a67));
      A1.u = make_uint4(pk2(e01), pk2(e23), pk2(e45), pk2(e67));
      const int swb = ((ks*4 + g) ^ (c & 7)) * 8;   // swizzled octet (conflict-free, proven)
      #pragma unroll
      for (int mt = 0; mt < 8; ++mt) {
        const short8 wf = *(const short8*)&Bs[(mt*16 + c)*128 + swb];
        acc[0][mt] = __builtin_amdgcn_mfma_f32_16x16x32_bf16(wf, A0.s, acc[0][mt], 0, 0, 0);
        acc[1][mt] = __builtin_amdgcn_mfma_f32_16x16x32_bf16(wf, A1.s, acc[1][mt], 0, 0, 0);
      }
    }

    // ---- epilogue: relu -> bf16 slab -> 4-k-step MFMA dot with Wout ----
    f32x4 osig[2];
    #pragma unroll
    for (int tm = 0; tm < 2; ++tm) {
      f32x4 oacc;
      oacc[0] = 0.f; oacc[1] = 0.f; oacc[2] = 0.f; oacc[3] = 0.f;
      #pragma unroll
      for (int kk = 0; kk < 4; ++kk) {
        #pragma unroll
        for (int i = 0; i < 2; ++i) {
          const f32x4 a = acc[tm][kk*2 + i];
          const f32x2 h01 = __builtin_elementwise_max((f32x2){a[0], a[1]}, zero2);
          const f32x2 h23 = __builtin_elementwise_max((f32x2){a[2], a[3]}, zero2);
          *(uint2*)&As2w[c*40 + i*16 + g*4] = make_uint2(pk2(h01), pk2(h23));
        }
        const short8 hbf = *(const short8*)&As2w[c*40 + g*8];
        oacc = __builtin_amdgcn_mfma_f32_16x16x32_bf16(wa[kk], hbf, oacc, 0, 0, 0);
      }
      osig[tm] = oacc;   // lanes g==0: {sigma_pre, c0, c1, c2}; g>0 lanes: zeros
    }

    // ---- online transmittance for these 32 samples (valid in lanes 0..15) ----
    const float sd0 = softplus_f(osig[0][0] + bd0) * d0;
    const float sd1 = softplus_f(osig[1][0] + bd0) * d1;
    float p0 = sd0;
    #pragma unroll
    for (int off = 1; off < 16; off <<= 1) {
      const float tpp = __shfl_up(p0, off, 16);
      p0 += ((L & 15) >= off) ? tpp : 0.f;
    }
    const float tot0 = __shfl(p0, 15);        // group-0 lane 15 -> all lanes
    float p1 = sd1;
    #pragma unroll
    for (int off = 1; off < 16; off <<= 1) {
      const float tpp = __shfl_up(p1, off, 16);
      p1 += ((L & 15) >= off) ? tpp : 0.f;
    }
    const float tot1 = __shfl(p1, 15);
    const float cs0 = csum + p0;
    const float cs1 = csum + tot0 + p1;
    csum += tot0 + tot1;
    const float w0 = fexp(sd0 - cs0) - fexp(-cs0);   // == 0 exactly when sd0 == 0
    const float w1 = fexp(sd1 - cs1) - fexp(-cs1);
    pw  += w0 + w1;
    pxc += w0 * sigmoid_f(osig[0][1] + cp0) + w1 * sigmoid_f(osig[1][1] + cp0);
    pyc += w0 * sigmoid_f(osig[0][2] + cp1) + w1 * sigmoid_f(osig[1][2] + cp1);
    pzc += w0 * sigmoid_f(osig[0][3] + cp2) + w1 * sigmoid_f(osig[1][3] + cp2);
  }

  // ---- per-ray reduction over lanes 0..15, store from lane 0 ----
  #pragma unroll
  for (int off = 1; off < 16; off <<= 1) {
    pw  += __shfl_xor(pw, off);
    pxc += __shfl_xor(pxc, off);
    pyc += __shfl_xor(pyc, off);
    pzc += __shfl_xor(pzc, off);
  }
  if (L == 0) {
    float4 o;
    o.x = active ? pxc : 0.f;
    o.y = active ? pyc : 0.f;
    o.z = active ? pzc : 0.f;
    o.w = active ? pw  : 0.f;
    *(float4*)&out[ray*4] = o;
  }
}

extern "C" void kernel_launch(void* const* d_in, const int* in_sizes, int n_in,
                              void* d_out, int out_size, void* d_ws, size_t ws_size,
                              hipStream_t stream) {
  const float* origins = (const float*)d_in[0];
  const float* dirs    = (const float*)d_in[1];
  const float* u       = (const float*)d_in[2];
  const float* W1      = (const float*)d_in[3];
  const float* b1      = (const float*)d_in[4];
  const float* W2      = (const float*)d_in[5];
  const float* b2      = (const float*)d_in[6];
  const float* Wd      = (const float*)d_in[7];
  const float* bd      = (const float*)d_in[8];
  const float* Wc      = (const float*)d_in[9];
  const float* bc      = (const float*)d_in[10];

  unsigned short* w2t      = (unsigned short*)d_ws;
  unsigned short* woutf    = (unsigned short*)((char*)d_ws + 32768);
  float*          rayp_all = (float*)((char*)d_ws + 36864);

  preprocess<<<64, 256, 0, stream>>>(W2, Wd, Wc, bc, origins, dirs,
                                     w2t, woutf, rayp_all);
  nerf_render<<<NRAYS/4, 256, 0, stream>>>(origins, dirs, u, W1, b1, b2, bd,
                                           w2t, woutf, rayp_all, (float*)d_out);
}